// Round 1
// baseline (233.782 us; speedup 1.0000x reference)
//
#include <hip/hip_runtime.h>
#include <math.h>

// Live dataflow (softmax over singleton axis == 1.0, so attn_out = v @ out_w.T + out_b):
//   x (64,8,2048) -> conv1(16,1,3,5 pad(1,2)) +bias,relu -> maxpool W/2 -> (64,16,8,1024)
//   -> conv2(32,16,3,5 pad(1,2)) +bias,relu -> maxpool W/2 -> mean(H,W) -> g (64,32)
//   -> glob = LN(relu(g@w_glob+b_glob)) -> v = glob@wv.T+bv -> ao = v@out_w.T+out_b
//   -> hmid = relu(ao@mlp_w1+mlp_b1) -> out = hmid@mlp_w2+mlp_b2  (64,10)

#define WT 64           // conv2 output columns per tile
#define NT 16           // 1024 / WT tiles
// LDS: h1s = 16 ic * 8 rows * 72 stride (68 used) ; bs = union(xs 8*144 + w1 240, w2s 7680)

__global__ __launch_bounds__(256, 2) void conv_fused(
    const float* __restrict__ x,
    const float* __restrict__ w1, const float* __restrict__ b1,
    const float* __restrict__ w2, const float* __restrict__ b2,
    float* __restrict__ gacc)
{
    const int wt  = blockIdx.x;      // 0..15
    const int b   = blockIdx.y;      // 0..63
    const int tid = threadIdx.x;     // 0..255
    const int w0  = wt * WT;         // conv2 column base

    __shared__ __align__(16) float h1s[16 * 8 * 72];   // [ic][r][72], cols 0..67 valid
    __shared__ __align__(16) float bs[7680];           // phase0: xs[8][144]+w1s[240]; phase2: w2s[16*15*32]
    float* xs  = bs;                 // 8*144
    float* w1s = bs + 1152;          // 240
    float* w2s = bs;                 // 7680, layout [ic][tap][oc]

    // ---- stage x tile (+halo) : x cols t0 .. t0+139 ----
    const int t0 = 2 * w0 - 6;
    for (int i = tid; i < 8 * 144; i += 256) {
        int r = i / 144, tl = i - r * 144;
        int t = t0 + tl;
        float v = 0.f;
        if (tl < 140 && t >= 0 && t < 2048) v = x[(b * 8 + r) * 2048 + t];
        xs[i] = v;
    }
    if (tid < 240) w1s[tid] = w1[tid];   // [ic*15 + kh*5 + kw]
    __syncthreads();

    // ---- phase 1: recompute conv1+bias+relu+maxpool tile into LDS ----
    // h1p local col wcl in [0,68) <-> global pooled col wc = w0-2+wcl
    for (int i = tid; i < 16 * 8 * 68; i += 256) {
        int ic  = i / (8 * 68);
        int rem = i - ic * (8 * 68);
        int r   = rem / 68, wcl = rem - r * 68;
        int wc  = w0 - 2 + wcl;
        float v = 0.f;
        if (wc >= 0 && wc < 1024) {
            float bias1 = b1[ic];
            float c0 = bias1, c1 = bias1;
            #pragma unroll
            for (int kh = 0; kh < 3; ++kh) {
                int rr = r + kh - 1;
                if (rr < 0 || rr >= 8) continue;
                const float* xrow = &xs[rr * 144 + 2 * wcl];
                const float* wr   = &w1s[ic * 15 + kh * 5];
                #pragma unroll
                for (int kw = 0; kw < 5; ++kw) {
                    float wv = wr[kw];
                    c0 = fmaf(xrow[kw],     wv, c0);
                    c1 = fmaf(xrow[kw + 1], wv, c1);
                }
            }
            v = fmaxf(fmaxf(c0, c1), 0.f);   // relu+maxpool (relu commutes with max)
        }
        h1s[(ic * 8 + r) * 72 + wcl] = v;
    }
    __syncthreads();

    // ---- load conv2 weights, layout [ic][tap][oc] (oc-last: conflict-free broadcast) ----
    for (int i = tid; i < 7680; i += 256) {
        int ic  = i / 480;
        int rem = i - ic * 480;
        int tap = rem >> 5;
        int oc2 = rem & 31;
        w2s[i] = w2[(oc2 * 16 + ic) * 15 + tap];
    }
    __syncthreads();

    // ---- phase 2: conv2 + bias + relu + maxpool + partial mean ----
    const int oc = tid >> 3;         // 0..31
    const int h  = tid & 7;          // 0..7
    float acc[WT];
    {
        float bias2 = b2[oc];
        #pragma unroll
        for (int j = 0; j < WT; ++j) acc[j] = bias2;
    }
    for (int ic = 0; ic < 16; ++ic) {
        #pragma unroll
        for (int kh = 0; kh < 3; ++kh) {
            int rr = h + kh - 1;
            if (rr < 0 || rr >= 8) continue;
            const float* wp = &w2s[(ic * 15 + kh * 5) * 32 + oc];
            float wv0 = wp[0], wv1 = wp[32], wv2 = wp[64], wv3 = wp[96], wv4 = wp[128];
            const float4* xr4 = (const float4*)&h1s[(ic * 8 + rr) * 72];
            float4 a = xr4[0];
            #pragma unroll
            for (int j4 = 0; j4 < 16; ++j4) {
                float4 bb = xr4[j4 + 1];
                acc[4*j4+0] = fmaf(a.x, wv0, fmaf(a.y, wv1, fmaf(a.z, wv2, fmaf(a.w,  wv3, fmaf(bb.x, wv4, acc[4*j4+0])))));
                acc[4*j4+1] = fmaf(a.y, wv0, fmaf(a.z, wv1, fmaf(a.w, wv2, fmaf(bb.x, wv3, fmaf(bb.y, wv4, acc[4*j4+1])))));
                acc[4*j4+2] = fmaf(a.z, wv0, fmaf(a.w, wv1, fmaf(bb.x, wv2, fmaf(bb.y, wv3, fmaf(bb.z, wv4, acc[4*j4+2])))));
                acc[4*j4+3] = fmaf(a.w, wv0, fmaf(bb.x, wv1, fmaf(bb.y, wv2, fmaf(bb.z, wv3, fmaf(bb.w, wv4, acc[4*j4+3])))));
                a = bb;
            }
        }
    }
    // relu + maxpool(2) + sum over this thread's 32 pooled outputs
    float part = 0.f;
    #pragma unroll
    for (int j = 0; j < 32; ++j)
        part += fmaxf(fmaxf(acc[2*j], acc[2*j+1]), 0.f);
    // reduce over h (8 consecutive lanes share oc)
    part += __shfl_down(part, 4);
    part += __shfl_down(part, 2);
    part += __shfl_down(part, 1);
    if (h == 0) atomicAdd(&gacc[b * 32 + oc], part);
}

__global__ void tail_kernel(
    const float* __restrict__ gacc,
    const float* __restrict__ w_glob, const float* __restrict__ b_glob,
    const float* __restrict__ g_glob, const float* __restrict__ be_glob,
    const float* __restrict__ in_proj_w, const float* __restrict__ in_proj_b,
    const float* __restrict__ out_w, const float* __restrict__ out_b,
    const float* __restrict__ mlp_w1, const float* __restrict__ mlp_b1,
    const float* __restrict__ mlp_w2, const float* __restrict__ mlp_b2,
    float* __restrict__ out)
{
    const int b = blockIdx.x;        // 0..63
    const int e = threadIdx.x;       // 0..63 (one wave)
    __shared__ float gs[32], glob_s[64], vs[64], aos[64], hms[32];

    if (e < 32) gs[e] = gacc[b * 32 + e] * (1.f / 4096.f);   // mean over 8*512
    __syncthreads();

    // glob_pre = relu(g @ w_glob + b_glob)
    float acc = b_glob[e];
    #pragma unroll
    for (int i = 0; i < 32; ++i) acc = fmaf(gs[i], w_glob[i * 64 + e], acc);
    acc = fmaxf(acc, 0.f);

    // layernorm over E=64 (one wave)
    float m = acc;
    #pragma unroll
    for (int k = 32; k >= 1; k >>= 1) m += __shfl_xor(m, k);
    m *= (1.f / 64.f);
    float d = acc - m;
    float vv = d * d;
    #pragma unroll
    for (int k = 32; k >= 1; k >>= 1) vv += __shfl_xor(vv, k);
    vv *= (1.f / 64.f);
    float gl = d * (1.f / sqrtf(vv + 1e-5f)) * g_glob[e] + be_glob[e];
    glob_s[e] = gl;
    __syncthreads();

    // v = glob @ wv.T + bv  (wv = in_proj_w rows 128..191)
    float vval = in_proj_b[128 + e];
    #pragma unroll
    for (int j = 0; j < 64; ++j) vval = fmaf(glob_s[j], in_proj_w[(128 + e) * 64 + j], vval);
    vs[e] = vval;
    __syncthreads();

    // attn_out = v @ out_w.T + out_b   (attn == 1 exactly)
    float ao = out_b[e];
    #pragma unroll
    for (int j = 0; j < 64; ++j) ao = fmaf(vs[j], out_w[e * 64 + j], ao);
    aos[e] = ao;
    __syncthreads();

    // hmid = relu(ao @ mlp_w1 + mlp_b1)
    if (e < 32) {
        float hm = mlp_b1[e];
        #pragma unroll
        for (int j = 0; j < 64; ++j) hm = fmaf(aos[j], mlp_w1[j * 32 + e], hm);
        hms[e] = fmaxf(hm, 0.f);
    }
    __syncthreads();

    // out = hmid @ mlp_w2 + mlp_b2
    if (e < 10) {
        float o = mlp_b2[e];
        #pragma unroll
        for (int i = 0; i < 32; ++i) o = fmaf(hms[i], mlp_w2[i * 10 + e], o);
        out[b * 10 + e] = o;
    }
}

extern "C" void kernel_launch(void* const* d_in, const int* in_sizes, int n_in,
                              void* d_out, int out_size, void* d_ws, size_t ws_size,
                              hipStream_t stream) {
    const float* x        = (const float*)d_in[0];
    const float* conv1_w  = (const float*)d_in[6];
    const float* conv1_b  = (const float*)d_in[7];
    const float* conv2_w  = (const float*)d_in[8];
    const float* conv2_b  = (const float*)d_in[9];
    const float* w_glob   = (const float*)d_in[10];
    const float* b_glob   = (const float*)d_in[11];
    const float* g_glob   = (const float*)d_in[12];
    const float* be_glob  = (const float*)d_in[13];
    const float* in_proj_w = (const float*)d_in[14];
    const float* in_proj_b = (const float*)d_in[15];
    const float* out_w    = (const float*)d_in[16];
    const float* out_b    = (const float*)d_in[17];
    const float* mlp_w1   = (const float*)d_in[18];
    const float* mlp_b1   = (const float*)d_in[19];
    const float* mlp_w2   = (const float*)d_in[20];
    const float* mlp_b2   = (const float*)d_in[21];

    float* gacc = (float*)d_ws;                      // 64*32 floats
    hipMemsetAsync(gacc, 0, 64 * 32 * sizeof(float), stream);

    dim3 grid(NT, 64);
    conv_fused<<<grid, 256, 0, stream>>>(x, conv1_w, conv1_b, conv2_w, conv2_b, gacc);

    tail_kernel<<<64, 64, 0, stream>>>(gacc, w_glob, b_glob, g_glob, be_glob,
                                       in_proj_w, in_proj_b, out_w, out_b,
                                       mlp_w1, mlp_b1, mlp_w2, mlp_b2,
                                       (float*)d_out);
}

// Round 3
// 202.409 us; speedup vs baseline: 1.1550x; 1.1550x over previous
//
#include <hip/hip_runtime.h>
#include <math.h>

// Live dataflow (softmax over singleton axis == 1.0, so attn_out = v @ out_w.T + out_b):
//   x (64,8,2048) -> conv1(16,1,3,5 pad(1,2)) +bias,relu -> maxpool W/2 -> (64,16,8,1024)
//   -> conv2(32,16,3,5 pad(1,2)) +bias,relu -> maxpool W/2 -> mean(H,W) -> g (64,32)
//   -> glob = LN(relu(g@w_glob+b_glob)) -> v = glob@wv.T+bv -> ao = v@out_w.T+out_b
//   -> hmid = relu(ao@mlp_w1+mlp_b1) -> out = hmid@mlp_w2+mlp_b2  (64,10)

#define WT 64                       // conv2 output columns per tile
#define NT 16                       // 1024 / WT tiles
#define H1S 76                      // h1s row stride: 76 % 32 = 12 -> 8 rows hit distinct bank groups
#define ZROW_OFF (16*8*H1S)         // 9728, shared zero row (for H-boundary taps)
#define XS_OFF   (ZROW_OFF + 80)    // 9808
#define W1_OFF   (XS_OFF + 8*144)   // 10960
#define LDS_TOT  (W1_OFF + 240)     // 11200 floats = 44800 B -> 3 blocks/CU

__global__ __launch_bounds__(256, 3) void conv_fused(
    const float* __restrict__ x,
    const float* __restrict__ w1, const float* __restrict__ b1,
    const float* __restrict__ w2, const float* __restrict__ b2,
    float* __restrict__ part)    // [64 b][32 oc][16 wt] race-free partials
{
    const int wt  = blockIdx.x;      // 0..15
    const int b   = blockIdx.y;      // 0..63
    const int tid = threadIdx.x;     // 0..255
    const int w0  = wt * WT;

    __shared__ __align__(16) float lds[LDS_TOT];
    float* h1s = lds;                // [ic*8+r][H1S], cols 0..67 valid; + zero row at ZROW_OFF
    float* xs  = lds + XS_OFF;       // 8*144
    float* w1s = lds + W1_OFF;       // 240

    // ---- phase 0: stage x tile (+halo), conv1 weights, zero row ----
    const int t0 = 2 * w0 - 6;
    for (int i = tid; i < 8 * 144; i += 256) {
        int r = i / 144, tl = i - r * 144;
        int t = t0 + tl;
        float v = 0.f;
        if (tl < 140 && t >= 0 && t < 2048) v = x[(b * 8 + r) * 2048 + t];
        xs[i] = v;
    }
    if (tid < 240) w1s[tid] = w1[tid];                       // [ic*15 + kh*5 + kw]
    if (tid < 80)  h1s[ZROW_OFF + tid] = 0.f;                // FULL 80-entry zero row
    __syncthreads();

    // ---- phase 1: conv1 + bias + relu + maxpool tile into LDS ----
    for (int i = tid; i < 16 * 8 * 68; i += 256) {
        int ic  = i / (8 * 68);
        int rem = i - ic * (8 * 68);
        int r   = rem / 68, wcl = rem - r * 68;
        int wc  = w0 - 2 + wcl;
        float v = 0.f;
        if (wc >= 0 && wc < 1024) {
            float bias1 = b1[ic];
            float c0 = bias1, c1 = bias1;
            #pragma unroll
            for (int kh = 0; kh < 3; ++kh) {
                int rr = r + kh - 1;
                if (rr < 0 || rr >= 8) continue;
                const float* xrow = &xs[rr * 144 + 2 * wcl];
                const float* wr   = &w1s[ic * 15 + kh * 5];
                #pragma unroll
                for (int kw = 0; kw < 5; ++kw) {
                    float wv = wr[kw];
                    c0 = fmaf(xrow[kw],     wv, c0);
                    c1 = fmaf(xrow[kw + 1], wv, c1);
                }
            }
            v = fmaxf(fmaxf(c0, c1), 0.f);   // relu+maxpool (relu commutes with max)
        }
        h1s[(ic * 8 + r) * H1S + wcl] = v;
    }
    __syncthreads();

    // ---- phase 2: conv2 (+bias,relu,pool,partial mean) ----
    // threads: h = tid&7, colgrp cg = (tid>>3)&7 (8 cols each); wave wv owns 8 ocs.
    // x in VGPRs (3 rows x 12 floats), weights via wave-uniform scalar loads (SGPRs).
    const int h   = tid & 7;
    const int cg  = (tid >> 3) & 7;
    const int wv  = __builtin_amdgcn_readfirstlane(tid >> 6);   // wave-uniform 0..3
    const int oc0 = wv * 8;

    float acc[8][8];
    #pragma unroll
    for (int o = 0; o < 8; ++o) {
        float bias2 = b2[oc0 + o];                  // scalar load
        #pragma unroll
        for (int c = 0; c < 8; ++c) acc[o][c] = bias2;
    }

    const int colbase = cg * 8;                     // input local col base (12 floats used)
    const int rowoff  = h * H1S + colbase;
    const int ztop    = (h > 0) ? 0 : 1;            // row h-1 invalid at h==0
    const int zbot    = (h < 7) ? 0 : 1;            // row h+1 invalid at h==7

    for (int ic = 0; ic < 16; ++ic) {
        const int icb = ic * 8 * H1S;
        const int ba  = ztop ? (ZROW_OFF + colbase) : (icb + rowoff - H1S);
        const int bb  = icb + rowoff;
        const int bc  = zbot ? (ZROW_OFF + colbase) : (icb + rowoff + H1S);

        float xr[3][12];
        #pragma unroll
        for (int q = 0; q < 3; ++q) {
            const int base = (q == 0) ? ba : (q == 1) ? bb : bc;
            float4 a0 = *(const float4*)&h1s[base];
            float4 a1 = *(const float4*)&h1s[base + 4];
            float4 a2 = *(const float4*)&h1s[base + 8];
            xr[q][0]=a0.x; xr[q][1]=a0.y; xr[q][2]=a0.z; xr[q][3]=a0.w;
            xr[q][4]=a1.x; xr[q][5]=a1.y; xr[q][6]=a1.z; xr[q][7]=a1.w;
            xr[q][8]=a2.x; xr[q][9]=a2.y; xr[q][10]=a2.z; xr[q][11]=a2.w;
        }

        #pragma unroll
        for (int o = 0; o < 8; ++o) {
            const float* wp = &w2[((oc0 + o) * 16 + ic) * 15];   // scalar base -> s_loads
            #pragma unroll
            for (int kh = 0; kh < 3; ++kh) {
                #pragma unroll
                for (int kw = 0; kw < 5; ++kw) {
                    const float wgt = wp[kh * 5 + kw];
                    #pragma unroll
                    for (int c = 0; c < 8; ++c)
                        acc[o][c] = fmaf(xr[kh][kw + c], wgt, acc[o][c]);
                }
            }
        }
    }

    // relu + maxpool(2) + sum over this thread's cols, then wave-reduce (h x cg = full tile)
    float pl[8];
    #pragma unroll
    for (int o = 0; o < 8; ++o) {
        float s = 0.f;
        #pragma unroll
        for (int c = 0; c < 4; ++c)
            s += fmaxf(fmaxf(acc[o][2 * c], acc[o][2 * c + 1]), 0.f);
        #pragma unroll
        for (int k = 32; k >= 1; k >>= 1) s += __shfl_xor(s, k);
        pl[o] = s;
    }
    if ((tid & 63) == 0) {
        #pragma unroll
        for (int o = 0; o < 8; ++o)
            part[(b * 32 + oc0 + o) * 16 + wt] = pl[o];
    }
}

__global__ void tail_kernel(
    const float* __restrict__ part,
    const float* __restrict__ w_glob, const float* __restrict__ b_glob,
    const float* __restrict__ g_glob, const float* __restrict__ be_glob,
    const float* __restrict__ in_proj_w, const float* __restrict__ in_proj_b,
    const float* __restrict__ out_w, const float* __restrict__ out_b,
    const float* __restrict__ mlp_w1, const float* __restrict__ mlp_b1,
    const float* __restrict__ mlp_w2, const float* __restrict__ mlp_b2,
    float* __restrict__ out)
{
    const int b = blockIdx.x;        // 0..63
    const int e = threadIdx.x;       // 0..63 (one wave)
    __shared__ float gs[32], glob_s[64], vs[64], aos[64], hms[32];

    if (e < 32) {
        float s = 0.f;
        #pragma unroll
        for (int t = 0; t < 16; ++t) s += part[(b * 32 + e) * 16 + t];
        gs[e] = s * (1.f / 4096.f);  // mean over 8*512
    }
    __syncthreads();

    // glob_pre = relu(g @ w_glob + b_glob)
    float acc = b_glob[e];
    #pragma unroll
    for (int i = 0; i < 32; ++i) acc = fmaf(gs[i], w_glob[i * 64 + e], acc);
    acc = fmaxf(acc, 0.f);

    // layernorm over E=64 (one wave)
    float m = acc;
    #pragma unroll
    for (int k = 32; k >= 1; k >>= 1) m += __shfl_xor(m, k);
    m *= (1.f / 64.f);
    float d = acc - m;
    float vv = d * d;
    #pragma unroll
    for (int k = 32; k >= 1; k >>= 1) vv += __shfl_xor(vv, k);
    vv *= (1.f / 64.f);
    float gl = d * (1.f / sqrtf(vv + 1e-5f)) * g_glob[e] + be_glob[e];
    glob_s[e] = gl;
    __syncthreads();

    // v = glob @ wv.T + bv  (wv = in_proj_w rows 128..191)
    float vval = in_proj_b[128 + e];
    #pragma unroll
    for (int j = 0; j < 64; ++j) vval = fmaf(glob_s[j], in_proj_w[(128 + e) * 64 + j], vval);
    vs[e] = vval;
    __syncthreads();

    // attn_out = v @ out_w.T + out_b   (attn == 1 exactly)
    float ao = out_b[e];
    #pragma unroll
    for (int j = 0; j < 64; ++j) ao = fmaf(vs[j], out_w[e * 64 + j], ao);
    aos[e] = ao;
    __syncthreads();

    // hmid = relu(ao @ mlp_w1 + mlp_b1)
    if (e < 32) {
        float hm = mlp_b1[e];
        #pragma unroll
        for (int j = 0; j < 64; ++j) hm = fmaf(aos[j], mlp_w1[j * 32 + e], hm);
        hms[e] = fmaxf(hm, 0.f);
    }
    __syncthreads();

    // out = hmid @ mlp_w2 + mlp_b2
    if (e < 10) {
        float o = mlp_b2[e];
        #pragma unroll
        for (int i = 0; i < 32; ++i) o = fmaf(hms[i], mlp_w2[i * 10 + e], o);
        out[b * 10 + e] = o;
    }
}

extern "C" void kernel_launch(void* const* d_in, const int* in_sizes, int n_in,
                              void* d_out, int out_size, void* d_ws, size_t ws_size,
                              hipStream_t stream) {
    const float* x        = (const float*)d_in[0];
    const float* conv1_w  = (const float*)d_in[6];
    const float* conv1_b  = (const float*)d_in[7];
    const float* conv2_w  = (const float*)d_in[8];
    const float* conv2_b  = (const float*)d_in[9];
    const float* w_glob   = (const float*)d_in[10];
    const float* b_glob   = (const float*)d_in[11];
    const float* g_glob   = (const float*)d_in[12];
    const float* be_glob  = (const float*)d_in[13];
    const float* in_proj_w = (const float*)d_in[14];
    const float* in_proj_b = (const float*)d_in[15];
    const float* out_w    = (const float*)d_in[16];
    const float* out_b    = (const float*)d_in[17];
    const float* mlp_w1   = (const float*)d_in[18];
    const float* mlp_b1   = (const float*)d_in[19];
    const float* mlp_w2   = (const float*)d_in[20];
    const float* mlp_b2   = (const float*)d_in[21];

    float* partials = (float*)d_ws;                  // 64*32*16 floats, fully written (no memset)

    dim3 grid(NT, 64);
    conv_fused<<<grid, 256, 0, stream>>>(x, conv1_w, conv1_b, conv2_w, conv2_b, partials);

    tail_kernel<<<64, 64, 0, stream>>>(partials, w_glob, b_glob, g_glob, be_glob,
                                       in_proj_w, in_proj_b, out_w, out_b,
                                       mlp_w1, mlp_b1, mlp_w2, mlp_b2,
                                       (float*)d_out);
}

// Round 4
// 158.554 us; speedup vs baseline: 1.4745x; 1.2766x over previous
//
#include <hip/hip_runtime.h>
#include <math.h>

// Live dataflow (softmax over singleton axis == 1.0):
//   x (64,8,2048) -> conv1(16,1,3,5 pad(1,2)) +bias,relu -> maxpool W/2 -> (64,16,8,1024)
//   -> conv2(32,16,3,5 pad(1,2)) +bias,relu -> maxpool W/2 -> mean(H,W) -> g (64,32)
//   -> glob = LN(relu(g@w_glob+b_glob)) -> v = glob@wv.T+bv -> ao = v@out_w.T+out_b
//   -> hmid = relu(ao@mlp_w1+mlp_b1) -> out = hmid@mlp_w2+mlp_b2  (64,10)
//
// conv2 via MFMA 32x32x16 bf16, bf16x3 split (Ah*Bh + Ah*Bl + Al*Bh), tap-major K.

typedef __attribute__((ext_vector_type(8)))  short bf16x8;
typedef __attribute__((ext_vector_type(16))) float f32x16;

#define WT 64
#define NT 16
// LDS byte offsets (all 16B aligned):
#define AH_OFF   0          // 15*64 frags * 16B = 15360
#define AL_OFF   15360
#define H1HI_OFF 30720      // 10 rows * 68 cols * 16 ic * 2B = 21760
#define H1LO_OFF 52480
#define XS_OFF   74240      // 8*144*4 = 4608
#define W1_OFF   78848      // 240*4 = 960
#define LDS_BYTES 79808     // -> 2 blocks/CU

__device__ __forceinline__ unsigned bf16_rne(float v) {
    unsigned u = __float_as_uint(v);
    return (u + 0x7fffu + ((u >> 16) & 1u)) >> 16;
}

__global__ __launch_bounds__(256, 2) void conv_fused(
    const float* __restrict__ x,
    const float* __restrict__ w1, const float* __restrict__ b1,
    const float* __restrict__ w2, const float* __restrict__ b2,
    float* __restrict__ part)    // [64 b][32 oc][16 wt][4 wave]
{
    const int wt  = blockIdx.x;      // 0..15
    const int b   = blockIdx.y;      // 0..63
    const int tid = threadIdx.x;     // 0..255
    const int w0  = wt * WT;

    __shared__ __align__(16) unsigned int ldsu[LDS_BYTES / 4];
    short* AH   = (short*)((char*)ldsu + AH_OFF);    // frag order: [(t*64+lane)*8 + j]
    short* AL   = (short*)((char*)ldsu + AL_OFF);
    short* h1hi = (short*)((char*)ldsu + H1HI_OFF);  // [(rr*68+c)*16 + ic], rr=0..9 (0,9 zero)
    short* h1lo = (short*)((char*)ldsu + H1LO_OFF);
    float* xs   = (float*)((char*)ldsu + XS_OFF);    // [8][144]
    float* w1s  = (float*)((char*)ldsu + W1_OFF);    // 240

    // ---- phase 0a: stage x tile. conv1 input cols t0..t0+139 (t0 = 2*w0-4) ----
    const int t0 = 2 * w0 - 4;
    for (int i = tid; i < 8 * 144; i += 256) {
        int r = i / 144, tl = i - r * 144;
        int t = t0 + tl;
        float v = 0.f;
        if (tl < 140 && t >= 0 && t < 2048) v = x[(b * 8 + r) * 2048 + t];
        xs[i] = v;
    }
    if (tid < 240) w1s[tid] = w1[tid];
    // zero rows rr=0 and rr=9 of h1hi/h1lo (row = 544 dwords)
    {
        unsigned int* hh = (unsigned int*)h1hi;
        unsigned int* hl = (unsigned int*)h1lo;
        for (int i = tid; i < 544; i += 256) {
            hh[i] = 0u; hh[4896 + i] = 0u;
            hl[i] = 0u; hl[4896 + i] = 0u;
        }
    }
    // ---- phase 0b: build A fragments (weights, hi/lo split, MFMA frag order) ----
    for (int i = tid; i < 15 * 64; i += 256) {
        int t    = i >> 6, lane = i & 63;
        int kh   = t / 5,  kw   = t - kh * 5;
        int oc   = lane & 31;
        int ic0  = (lane >> 5) * 8;
        bf16x8 hv, lv;
        #pragma unroll
        for (int j = 0; j < 8; ++j) {
            float v  = w2[((oc * 16 + ic0 + j) * 3 + kh) * 5 + kw];
            unsigned hb = bf16_rne(v);
            float    hf = __uint_as_float(hb << 16);
            unsigned lb = bf16_rne(v - hf);
            hv[j] = (short)hb;
            lv[j] = (short)lb;
        }
        *(bf16x8*)&AH[i * 8] = hv;
        *(bf16x8*)&AL[i * 8] = lv;
    }
    __syncthreads();

    // ---- phase 1: conv1 + bias + relu + maxpool -> h1 (bf16 hi/lo, [row][col][ic]) ----
    // pooled col c in [0,68) <-> global pooled col wc = w0-1+c ; stored at row rr = r+1
    for (int i = tid; i < 16 * 8 * 68; i += 256) {
        int ic = i & 15;
        int j  = i >> 4;             // 0..543
        int c  = j % 68;
        int r  = j / 68;             // 0..7
        int wc = w0 - 1 + c;
        float v = 0.f;
        if (wc >= 0 && wc < 1024) {
            float bias1 = b1[ic];
            float c0 = bias1, c1 = bias1;
            #pragma unroll
            for (int kh = 0; kh < 3; ++kh) {
                int rr = r + kh - 1;
                if (rr < 0 || rr >= 8) continue;
                const float* xrow = &xs[rr * 144 + 2 * c];
                const float* wr   = &w1s[ic * 15 + kh * 5];
                #pragma unroll
                for (int kw = 0; kw < 5; ++kw) {
                    float wv = wr[kw];
                    c0 = fmaf(xrow[kw],     wv, c0);
                    c1 = fmaf(xrow[kw + 1], wv, c1);
                }
            }
            v = fmaxf(fmaxf(c0, c1), 0.f);
        }
        unsigned hb = bf16_rne(v);
        float    hf = __uint_as_float(hb << 16);
        unsigned lb = bf16_rne(v - hf);
        int idx = ((r + 1) * 68 + c) * 16 + ic;
        h1hi[idx] = (short)hb;
        h1lo[idx] = (short)lb;
    }
    __syncthreads();

    // ---- phase 2: conv2 via MFMA. wave handles h rows {2w,2w+1} x wn0 {0,32} ----
    const int lane  = tid & 63;
    const int wave  = tid >> 6;
    const int laneN = lane & 31;
    const int icoff = (lane >> 5) * 8;   // k-half
    const int half  = lane >> 5;

    f32x16 acc[4];
    #pragma unroll
    for (int nt = 0; nt < 4; ++nt)
        #pragma unroll
        for (int r = 0; r < 16; ++r) acc[nt][r] = 0.f;

    for (int t = 0; t < 15; ++t) {
        int kh = t / 5, kw = t - kh * 5;               // wave-uniform
        bf16x8 ah = *(const bf16x8*)&AH[(t * 64 + lane) * 8];
        bf16x8 al = *(const bf16x8*)&AL[(t * 64 + lane) * 8];
        #pragma unroll
        for (int nt = 0; nt < 4; ++nt) {
            int hrow = 2 * wave + (nt >> 1);
            int wn0  = (nt & 1) * 32;
            int idx  = ((hrow + kh) * 68 + wn0 + laneN + kw) * 16 + icoff;
            bf16x8 bh = *(const bf16x8*)&h1hi[idx];
            bf16x8 bl = *(const bf16x8*)&h1lo[idx];
            acc[nt] = __builtin_amdgcn_mfma_f32_32x32x16_bf16(ah, bh, acc[nt], 0, 0, 0);
            acc[nt] = __builtin_amdgcn_mfma_f32_32x32x16_bf16(ah, bl, acc[nt], 0, 0, 0);
            acc[nt] = __builtin_amdgcn_mfma_f32_32x32x16_bf16(al, bh, acc[nt], 0, 0, 0);
        }
    }

    // ---- epilogue: +bias, relu(maxpool) via xor-1 lane pair, sum over n, per-oc write ----
    float b2v[16], sums[16];
    #pragma unroll
    for (int r = 0; r < 16; ++r) {
        b2v[r]  = b2[(r & 3) + 8 * (r >> 2) + 4 * half];
        sums[r] = 0.f;
    }
    #pragma unroll
    for (int nt = 0; nt < 4; ++nt)
        #pragma unroll
        for (int r = 0; r < 16; ++r) {
            float d = acc[nt][r] + b2v[r];
            float o = fmaxf(fmaxf(d, __shfl_xor(d, 1)), 0.f);  // pool pair (n, n^1) + relu
            sums[r] += o;                                       // counts each pair twice
        }
    #pragma unroll
    for (int r = 0; r < 16; ++r)
        #pragma unroll
        for (int k = 1; k <= 16; k <<= 1)
            sums[r] += __shfl_xor(sums[r], k);                  // sum over n=0..31 (stays in half)
    if (laneN == 0) {
        #pragma unroll
        for (int r = 0; r < 16; ++r) {
            int oc = (r & 3) + 8 * (r >> 2) + 4 * half;
            part[((b * 32 + oc) * 16 + wt) * 4 + wave] = 0.5f * sums[r];
        }
    }
}

__global__ void tail_kernel(
    const float* __restrict__ part,
    const float* __restrict__ w_glob, const float* __restrict__ b_glob,
    const float* __restrict__ g_glob, const float* __restrict__ be_glob,
    const float* __restrict__ in_proj_w, const float* __restrict__ in_proj_b,
    const float* __restrict__ out_w, const float* __restrict__ out_b,
    const float* __restrict__ mlp_w1, const float* __restrict__ mlp_b1,
    const float* __restrict__ mlp_w2, const float* __restrict__ mlp_b2,
    float* __restrict__ out)
{
    const int b = blockIdx.x;        // 0..63
    const int e = threadIdx.x;       // 0..63 (one wave)
    __shared__ float gs[32], glob_s[64], vs[64], aos[64], hms[32];

    if (e < 32) {
        float s = 0.f;
        #pragma unroll
        for (int t = 0; t < 64; ++t) s += part[(b * 32 + e) * 64 + t];
        gs[e] = s * (1.f / 4096.f);  // mean over 8*512
    }
    __syncthreads();

    // glob_pre = relu(g @ w_glob + b_glob)
    float acc = b_glob[e];
    #pragma unroll
    for (int i = 0; i < 32; ++i) acc = fmaf(gs[i], w_glob[i * 64 + e], acc);
    acc = fmaxf(acc, 0.f);

    // layernorm over E=64 (one wave)
    float m = acc;
    #pragma unroll
    for (int k = 32; k >= 1; k >>= 1) m += __shfl_xor(m, k);
    m *= (1.f / 64.f);
    float d = acc - m;
    float vv = d * d;
    #pragma unroll
    for (int k = 32; k >= 1; k >>= 1) vv += __shfl_xor(vv, k);
    vv *= (1.f / 64.f);
    float gl = d * (1.f / sqrtf(vv + 1e-5f)) * g_glob[e] + be_glob[e];
    glob_s[e] = gl;
    __syncthreads();

    // v = glob @ wv.T + bv  (wv = in_proj_w rows 128..191)
    float vval = in_proj_b[128 + e];
    #pragma unroll
    for (int j = 0; j < 64; ++j) vval = fmaf(glob_s[j], in_proj_w[(128 + e) * 64 + j], vval);
    vs[e] = vval;
    __syncthreads();

    // attn_out = v @ out_w.T + out_b   (attn == 1 exactly)
    float ao = out_b[e];
    #pragma unroll
    for (int j = 0; j < 64; ++j) ao = fmaf(vs[j], out_w[e * 64 + j], ao);
    aos[e] = ao;
    __syncthreads();

    // hmid = relu(ao @ mlp_w1 + mlp_b1)
    if (e < 32) {
        float hm = mlp_b1[e];
        #pragma unroll
        for (int j = 0; j < 64; ++j) hm = fmaf(aos[j], mlp_w1[j * 32 + e], hm);
        hms[e] = fmaxf(hm, 0.f);
    }
    __syncthreads();

    // out = hmid @ mlp_w2 + mlp_b2
    if (e < 10) {
        float o = mlp_b2[e];
        #pragma unroll
        for (int i = 0; i < 32; ++i) o = fmaf(hms[i], mlp_w2[i * 10 + e], o);
        out[b * 10 + e] = o;
    }
}

extern "C" void kernel_launch(void* const* d_in, const int* in_sizes, int n_in,
                              void* d_out, int out_size, void* d_ws, size_t ws_size,
                              hipStream_t stream) {
    const float* x        = (const float*)d_in[0];
    const float* conv1_w  = (const float*)d_in[6];
    const float* conv1_b  = (const float*)d_in[7];
    const float* conv2_w  = (const float*)d_in[8];
    const float* conv2_b  = (const float*)d_in[9];
    const float* w_glob   = (const float*)d_in[10];
    const float* b_glob   = (const float*)d_in[11];
    const float* g_glob   = (const float*)d_in[12];
    const float* be_glob  = (const float*)d_in[13];
    const float* in_proj_w = (const float*)d_in[14];
    const float* in_proj_b = (const float*)d_in[15];
    const float* out_w    = (const float*)d_in[16];
    const float* out_b    = (const float*)d_in[17];
    const float* mlp_w1   = (const float*)d_in[18];
    const float* mlp_b1   = (const float*)d_in[19];
    const float* mlp_w2   = (const float*)d_in[20];
    const float* mlp_b2   = (const float*)d_in[21];

    float* partials = (float*)d_ws;                  // 64*32*16*4 floats, fully written

    dim3 grid(NT, 64);
    conv_fused<<<grid, 256, 0, stream>>>(x, conv1_w, conv1_b, conv2_w, conv2_b, partials);

    tail_kernel<<<64, 64, 0, stream>>>(partials, w_glob, b_glob, g_glob, be_glob,
                                       in_proj_w, in_proj_b, out_w, out_b,
                                       mlp_w1, mlp_b1, mlp_w2, mlp_b2,
                                       (float*)d_out);
}

// Round 5
// 132.696 us; speedup vs baseline: 1.7618x; 1.1949x over previous
//
#include <hip/hip_runtime.h>
#include <math.h>

// Live dataflow (softmax over singleton axis == 1.0):
//   x (64,8,2048) -> conv1(16,1,3,5 pad(1,2)) +bias,relu -> maxpool W/2 -> (64,16,8,1024)
//   -> conv2(32,16,3,5 pad(1,2)) +bias,relu -> maxpool W/2 -> mean(H,W) -> g (64,32)
//   -> glob = LN(relu(g@w_glob+b_glob)) -> v = glob@wv.T+bv -> ao = v@out_w.T+out_b
//   -> hmid = relu(ao@mlp_w1+mlp_b1) -> out = hmid@mlp_w2+mlp_b2  (64,10)
//
// conv2 via MFMA 32x32x16 bf16, bf16x3 split (Ah*Bh + Ah*Bl + Al*Bh), tap-major K.
// Geometry: h1 local col c <-> global pooled col wc = w0-2+c (round-3-verified mapping).

typedef __attribute__((ext_vector_type(8)))  short bf16x8;
typedef __attribute__((ext_vector_type(16))) float f32x16;

#define WT 64
#define NT 16
// LDS byte offsets (16B aligned):
#define AH_OFF   0          // 15*64*8 bf16 = 15360 B
#define AL_OFF   15360
#define H1HI_OFF 30720      // 10 rows * 68 cols * 16 ic * 2B = 21760
#define H1LO_OFF 52480
#define XS_OFF   74240      // 8*144*4 = 4608
#define LDS_BYTES 78848     // -> 2 blocks/CU

__device__ __forceinline__ unsigned bf16_rne(float v) {
    unsigned u = __float_as_uint(v);
    return (u + 0x7fffu + ((u >> 16) & 1u)) >> 16;
}

// Build conv2-weight MFMA A-fragments (hi/lo bf16 split) once: fragg[2][15][64][8]
__global__ void prep_frags(const float* __restrict__ w2, short* __restrict__ fragg) {
    const int t    = blockIdx.x;       // 0..14 (tap)
    const int lane = threadIdx.x;      // 0..63
    const int kh   = t / 5, kw = t - kh * 5;
    const int oc   = lane & 31;
    const int ic0  = (lane >> 5) * 8;
    bf16x8 hv, lv;
    #pragma unroll
    for (int j = 0; j < 8; ++j) {
        float v  = w2[((oc * 16 + ic0 + j) * 3 + kh) * 5 + kw];
        unsigned hb = bf16_rne(v);
        float    hf = __uint_as_float(hb << 16);
        unsigned lb = bf16_rne(v - hf);
        hv[j] = (short)hb;
        lv[j] = (short)lb;
    }
    *(bf16x8*)&fragg[(t * 64 + lane) * 8]        = hv;
    *(bf16x8*)&fragg[7680 + (t * 64 + lane) * 8] = lv;
}

__global__ __launch_bounds__(256, 2) void conv_fused(
    const float* __restrict__ x,
    const float* __restrict__ w1, const float* __restrict__ b1,
    const float* __restrict__ b2,
    const short* __restrict__ fragg,
    float* __restrict__ part)    // [64 b][32 oc][16 wt][4 wave]
{
    const int wt  = blockIdx.x;      // 0..15
    const int b   = blockIdx.y;      // 0..63
    const int tid = threadIdx.x;     // 0..255
    const int w0  = wt * WT;

    __shared__ __align__(16) unsigned int ldsu[LDS_BYTES / 4];
    short* h1hi = (short*)((char*)ldsu + H1HI_OFF);  // [(rr*68+c)*16 + ic], rr=0..9 (0,9 zero)
    short* h1lo = (short*)((char*)ldsu + H1LO_OFF);
    float* xs   = (float*)((char*)ldsu + XS_OFF);    // [8][144]
    short* AH   = (short*)((char*)ldsu + AH_OFF);
    short* AL   = (short*)((char*)ldsu + AL_OFF);

    // ---- per-thread conv1 weights (hoisted out of the loop) ----
    const int ic1 = tid & 15;        // phase-1 channel
    const int s   = tid >> 4;        // phase-1 slot 0..15
    float wreg[15];
    #pragma unroll
    for (int k = 0; k < 15; ++k) wreg[k] = w1[ic1 * 15 + k];
    const float bias1 = b1[ic1];

    // ---- phase 0: stage x tile (cols t0..t0+139), copy A-fragments, zero pad rows ----
    const int t0 = 2 * w0 - 6;
    for (int i = tid; i < 8 * 144; i += 256) {
        int r = i / 144, tl = i - r * 144;
        int t = t0 + tl;
        float v = 0.f;
        if (tl < 140 && t >= 0 && t < 2048) v = x[(b * 8 + r) * 2048 + t];
        xs[i] = v;
    }
    {
        float4* dst = (float4*)ldsu;                 // AH then AL, contiguous 30720 B
        const float4* src = (const float4*)fragg;
        for (int i = tid; i < 1920; i += 256) dst[i] = src[i];
    }
    {
        unsigned int* hh = (unsigned int*)h1hi;
        unsigned int* hl = (unsigned int*)h1lo;
        for (int i = tid; i < 544; i += 256) {       // rows rr=0 and rr=9 (544 dwords each)
            hh[i] = 0u; hh[4896 + i] = 0u;
            hl[i] = 0u; hl[4896 + i] = 0u;
        }
    }
    __syncthreads();

    // ---- phase 1: conv1 + bias + relu + maxpool -> h1 (bf16 hi/lo) ----
    // items j = r*17 + c4 (r 0..7, c4 0..16, cols c=4*c4..4*c4+3); this thread: j = s, s+16, ...
    {
        int r = 0, c4 = s;
        while (c4 >= 17) { c4 -= 17; ++r; }
        for (int j = s; j < 136; j += 16) {
            const int cb = c4 * 8;                   // xs col base (float4 aligned)
            float xv[3][12];
            #pragma unroll
            for (int q = 0; q < 3; ++q) {
                int rr = r + q - 1;
                if (rr >= 0 && rr < 8) {
                    const float4* p = (const float4*)&xs[rr * 144 + cb];
                    float4 a0 = p[0], a1 = p[1], a2 = p[2];
                    xv[q][0]=a0.x; xv[q][1]=a0.y; xv[q][2]=a0.z; xv[q][3]=a0.w;
                    xv[q][4]=a1.x; xv[q][5]=a1.y; xv[q][6]=a1.z; xv[q][7]=a1.w;
                    xv[q][8]=a2.x; xv[q][9]=a2.y; xv[q][10]=a2.z; xv[q][11]=a2.w;
                } else {
                    #pragma unroll
                    for (int z = 0; z < 12; ++z) xv[q][z] = 0.f;
                }
            }
            const int ib = ((r + 1) * 68 + 4 * c4) * 16 + ic1;
            #pragma unroll
            for (int cc = 0; cc < 4; ++cc) {
                float c0 = bias1, c1 = bias1;
                #pragma unroll
                for (int kh = 0; kh < 3; ++kh)
                    #pragma unroll
                    for (int kw = 0; kw < 5; ++kw) {
                        float wgt = wreg[kh * 5 + kw];
                        c0 = fmaf(xv[kh][2 * cc + kw],     wgt, c0);
                        c1 = fmaf(xv[kh][2 * cc + kw + 1], wgt, c1);
                    }
                float v = fmaxf(fmaxf(c0, c1), 0.f);
                int wc = w0 - 2 + 4 * c4 + cc;
                if (wc < 0 || wc >= 1024) v = 0.f;
                unsigned hb = bf16_rne(v);
                float    hf = __uint_as_float(hb << 16);
                unsigned lb = bf16_rne(v - hf);
                h1hi[ib + cc * 16] = (short)hb;
                h1lo[ib + cc * 16] = (short)lb;
            }
            c4 += 16;
            if (c4 >= 17) { c4 -= 17; ++r; }
        }
    }
    __syncthreads();

    // ---- phase 2: conv2 via MFMA. wave handles h rows {2w,2w+1} x wn0 {0,32} ----
    const int lane  = tid & 63;
    const int wave  = tid >> 6;
    const int laneN = lane & 31;
    const int icoff = (lane >> 5) * 8;
    const int half  = lane >> 5;

    f32x16 acc[4];
    #pragma unroll
    for (int nt = 0; nt < 4; ++nt)
        #pragma unroll
        for (int r = 0; r < 16; ++r) acc[nt][r] = 0.f;

    for (int t = 0; t < 15; ++t) {
        int kh = t / 5, kw = t - kh * 5;               // wave-uniform
        bf16x8 ah = *(const bf16x8*)&AH[(t * 64 + lane) * 8];
        bf16x8 al = *(const bf16x8*)&AL[(t * 64 + lane) * 8];
        #pragma unroll
        for (int nt = 0; nt < 4; ++nt) {
            int hrow = 2 * wave + (nt >> 1);
            int wn0  = (nt & 1) * 32;
            int idx  = ((hrow + kh) * 68 + wn0 + laneN + kw) * 16 + icoff;
            bf16x8 bh = *(const bf16x8*)&h1hi[idx];
            bf16x8 bl = *(const bf16x8*)&h1lo[idx];
            acc[nt] = __builtin_amdgcn_mfma_f32_32x32x16_bf16(ah, bh, acc[nt], 0, 0, 0);
            acc[nt] = __builtin_amdgcn_mfma_f32_32x32x16_bf16(ah, bl, acc[nt], 0, 0, 0);
            acc[nt] = __builtin_amdgcn_mfma_f32_32x32x16_bf16(al, bh, acc[nt], 0, 0, 0);
        }
    }

    // ---- epilogue: +bias, relu(maxpool) via xor-1 pair, sum over n, per-oc write ----
    float b2v[16], sums[16];
    #pragma unroll
    for (int r = 0; r < 16; ++r) {
        b2v[r]  = b2[(r & 3) + 8 * (r >> 2) + 4 * half];
        sums[r] = 0.f;
    }
    #pragma unroll
    for (int nt = 0; nt < 4; ++nt)
        #pragma unroll
        for (int r = 0; r < 16; ++r) {
            float d = acc[nt][r] + b2v[r];
            float o = fmaxf(fmaxf(d, __shfl_xor(d, 1)), 0.f);  // pool pair + relu
            sums[r] += o;                                       // counts each pair twice
        }
    #pragma unroll
    for (int r = 0; r < 16; ++r)
        #pragma unroll
        for (int k = 1; k <= 16; k <<= 1)
            sums[r] += __shfl_xor(sums[r], k);                  // sum over n (stays in half)
    if (laneN == 0) {
        #pragma unroll
        for (int r = 0; r < 16; ++r) {
            int oc = (r & 3) + 8 * (r >> 2) + 4 * half;
            part[((b * 32 + oc) * 16 + wt) * 4 + wave] = 0.5f * sums[r];
        }
    }
}

__global__ void tail_kernel(
    const float* __restrict__ part,
    const float* __restrict__ w_glob, const float* __restrict__ b_glob,
    const float* __restrict__ g_glob, const float* __restrict__ be_glob,
    const float* __restrict__ in_proj_w, const float* __restrict__ in_proj_b,
    const float* __restrict__ out_w, const float* __restrict__ out_b,
    const float* __restrict__ mlp_w1, const float* __restrict__ mlp_b1,
    const float* __restrict__ mlp_w2, const float* __restrict__ mlp_b2,
    float* __restrict__ out)
{
    const int b = blockIdx.x;        // 0..63
    const int e = threadIdx.x;       // 0..63 (one wave)
    __shared__ float gs[32], glob_s[64], vs[64], aos[64], hms[32];

    if (e < 32) {
        float sm = 0.f;
        #pragma unroll
        for (int t = 0; t < 64; ++t) sm += part[(b * 32 + e) * 64 + t];
        gs[e] = sm * (1.f / 4096.f);  // mean over 8*512
    }
    __syncthreads();

    float acc = b_glob[e];
    #pragma unroll
    for (int i = 0; i < 32; ++i) acc = fmaf(gs[i], w_glob[i * 64 + e], acc);
    acc = fmaxf(acc, 0.f);

    float m = acc;
    #pragma unroll
    for (int k = 32; k >= 1; k >>= 1) m += __shfl_xor(m, k);
    m *= (1.f / 64.f);
    float d = acc - m;
    float vv = d * d;
    #pragma unroll
    for (int k = 32; k >= 1; k >>= 1) vv += __shfl_xor(vv, k);
    vv *= (1.f / 64.f);
    float gl = d * (1.f / sqrtf(vv + 1e-5f)) * g_glob[e] + be_glob[e];
    glob_s[e] = gl;
    __syncthreads();

    float vval = in_proj_b[128 + e];
    #pragma unroll
    for (int j = 0; j < 64; ++j) vval = fmaf(glob_s[j], in_proj_w[(128 + e) * 64 + j], vval);
    vs[e] = vval;
    __syncthreads();

    float ao = out_b[e];
    #pragma unroll
    for (int j = 0; j < 64; ++j) ao = fmaf(vs[j], out_w[e * 64 + j], ao);
    aos[e] = ao;
    __syncthreads();

    if (e < 32) {
        float hm = mlp_b1[e];
        #pragma unroll
        for (int j = 0; j < 64; ++j) hm = fmaf(aos[j], mlp_w1[j * 32 + e], hm);
        hms[e] = fmaxf(hm, 0.f);
    }
    __syncthreads();

    if (e < 10) {
        float o = mlp_b2[e];
        #pragma unroll
        for (int i = 0; i < 32; ++i) o = fmaf(hms[i], mlp_w2[i * 10 + e], o);
        out[b * 10 + e] = o;
    }
}

extern "C" void kernel_launch(void* const* d_in, const int* in_sizes, int n_in,
                              void* d_out, int out_size, void* d_ws, size_t ws_size,
                              hipStream_t stream) {
    const float* x        = (const float*)d_in[0];
    const float* conv1_w  = (const float*)d_in[6];
    const float* conv1_b  = (const float*)d_in[7];
    const float* conv2_w  = (const float*)d_in[8];
    const float* conv2_b  = (const float*)d_in[9];
    const float* w_glob   = (const float*)d_in[10];
    const float* b_glob   = (const float*)d_in[11];
    const float* g_glob   = (const float*)d_in[12];
    const float* be_glob  = (const float*)d_in[13];
    const float* in_proj_w = (const float*)d_in[14];
    const float* in_proj_b = (const float*)d_in[15];
    const float* out_w    = (const float*)d_in[16];
    const float* out_b    = (const float*)d_in[17];
    const float* mlp_w1   = (const float*)d_in[18];
    const float* mlp_b1   = (const float*)d_in[19];
    const float* mlp_w2   = (const float*)d_in[20];
    const float* mlp_b2   = (const float*)d_in[21];

    short* fragg    = (short*)d_ws;                              // 30720 B
    float* partials = (float*)((char*)d_ws + 30720);             // 64*32*16*4 floats

    prep_frags<<<15, 64, 0, stream>>>(conv2_w, fragg);

    dim3 grid(NT, 64);
    conv_fused<<<grid, 256, 0, stream>>>(x, conv1_w, conv1_b, conv2_b, fragg, partials);

    tail_kernel<<<64, 64, 0, stream>>>(partials, w_glob, b_glob, g_glob, be_glob,
                                       in_proj_w, in_proj_b, out_w, out_b,
                                       mlp_w1, mlp_b1, mlp_w2, mlp_b2,
                                       (float*)d_out);
}

// Round 6
// 124.880 us; speedup vs baseline: 1.8720x; 1.0626x over previous
//
#include <hip/hip_runtime.h>
#include <math.h>

// Live dataflow (softmax over singleton axis == 1.0):
//   x (64,8,2048) -> conv1(16,1,3,5 pad(1,2)) +bias,relu -> maxpool W/2 -> (64,16,8,1024)
//   -> conv2(32,16,3,5 pad(1,2)) +bias,relu -> maxpool W/2 -> mean(H,W) -> g (64,32)
//   -> glob = LN(relu(g@w_glob+b_glob)) -> v = glob@wv.T+bv -> ao = v@out_w.T+out_b
//   -> hmid = relu(ao@mlp_w1+mlp_b1) -> out = hmid@mlp_w2+mlp_b2  (64,10)
//
// conv2 via single-product fp16 MFMA 32x32x16 (error budget: |w*h|~0.0075, 240-term sum,
// fp16 rel 2^-11 -> feat err ~1e-4, averaged by mean/4096 downstream; threshold 7.5e-4).
// A-fragments (weights) live in global (L1/L2-resident, 1-deep prefetch), h1 fp16 in LDS.
// Geometry: h1 local col c <-> global pooled col wc = w0-2+c (round-3-verified mapping).

typedef __attribute__((ext_vector_type(8)))  _Float16 f16x8;
typedef __attribute__((ext_vector_type(16))) float    f32x16;

#define WT 64
#define NT 16
// LDS byte offsets (16B aligned):
#define H1_OFF   0          // 10 rows * 68 cols * 16 ic * 2B = 21760
#define XS_OFF   21760      // 8*144*4 = 4608
#define LDS_BYTES 26368     // -> LDS allows 6 blocks/CU; launch_bounds targets 4

// Build conv2-weight fp16 MFMA A-fragments once: fragg[15][64][8]
__global__ void prep_frags(const float* __restrict__ w2, _Float16* __restrict__ fragg) {
    const int t    = blockIdx.x;       // 0..14 (tap)
    const int lane = threadIdx.x;      // 0..63
    const int kh   = t / 5, kw = t - kh * 5;
    const int oc   = lane & 31;
    const int ic0  = (lane >> 5) * 8;
    f16x8 hv;
    #pragma unroll
    for (int j = 0; j < 8; ++j)
        hv[j] = (_Float16)w2[((oc * 16 + ic0 + j) * 3 + kh) * 5 + kw];
    *(f16x8*)&fragg[(t * 64 + lane) * 8] = hv;
}

__global__ __launch_bounds__(256, 4) void conv_fused(
    const float* __restrict__ x,
    const float* __restrict__ w1, const float* __restrict__ b1,
    const float* __restrict__ b2,
    const _Float16* __restrict__ fragg,
    float* __restrict__ part)    // [64 b][32 oc][16 wt][4 wave]
{
    const int wt  = blockIdx.x;      // 0..15
    const int b   = blockIdx.y;      // 0..63
    const int tid = threadIdx.x;     // 0..255
    const int w0  = wt * WT;

    __shared__ __align__(16) unsigned int ldsu[LDS_BYTES / 4];
    _Float16* h1 = (_Float16*)((char*)ldsu + H1_OFF);  // [(rr*68+c)*16 + ic], rr=0..9 (0,9 zero)
    float*    xs = (float*)((char*)ldsu + XS_OFF);     // [8][144]

    // ---- per-thread conv1 weights (hoisted) ----
    const int ic1 = tid & 15;        // phase-1 channel
    const int s   = tid >> 4;        // phase-1 slot 0..15
    float wreg[15];
    #pragma unroll
    for (int k = 0; k < 15; ++k) wreg[k] = w1[ic1 * 15 + k];
    const float bias1 = b1[ic1];

    // ---- phase 0: stage x tile (cols t0..t0+139), zero pad rows rr=0,9 ----
    const int t0 = 2 * w0 - 6;
    for (int i = tid; i < 8 * 144; i += 256) {
        int r = i / 144, tl = i - r * 144;
        int t = t0 + tl;
        float v = 0.f;
        if (tl < 140 && t >= 0 && t < 2048) v = x[(b * 8 + r) * 2048 + t];
        xs[i] = v;
    }
    {
        unsigned int* hh = (unsigned int*)h1;
        for (int i = tid; i < 544; i += 256) {       // each padded row = 544 dwords
            hh[i] = 0u; hh[4896 + i] = 0u;
        }
    }
    __syncthreads();

    // ---- phase 1: conv1 + bias + relu + maxpool -> h1 (fp16) ----
    // items j = r*17 + c4 (r 0..7, c4 0..16, cols c=4*c4..4*c4+3); this thread: j = s, s+16, ...
    {
        int r = 0, c4 = s;
        while (c4 >= 17) { c4 -= 17; ++r; }
        for (int j = s; j < 136; j += 16) {
            const int cb = c4 * 8;                   // xs col base (float4 aligned)
            float xv[3][12];
            #pragma unroll
            for (int q = 0; q < 3; ++q) {
                int rr = r + q - 1;
                if (rr >= 0 && rr < 8) {
                    const float4* p = (const float4*)&xs[rr * 144 + cb];
                    float4 a0 = p[0], a1 = p[1], a2 = p[2];
                    xv[q][0]=a0.x; xv[q][1]=a0.y; xv[q][2]=a0.z; xv[q][3]=a0.w;
                    xv[q][4]=a1.x; xv[q][5]=a1.y; xv[q][6]=a1.z; xv[q][7]=a1.w;
                    xv[q][8]=a2.x; xv[q][9]=a2.y; xv[q][10]=a2.z; xv[q][11]=a2.w;
                } else {
                    #pragma unroll
                    for (int z = 0; z < 12; ++z) xv[q][z] = 0.f;
                }
            }
            const int ib = ((r + 1) * 68 + 4 * c4) * 16 + ic1;
            #pragma unroll
            for (int cc = 0; cc < 4; ++cc) {
                float c0 = bias1, c1 = bias1;
                #pragma unroll
                for (int kh = 0; kh < 3; ++kh)
                    #pragma unroll
                    for (int kw = 0; kw < 5; ++kw) {
                        float wgt = wreg[kh * 5 + kw];
                        c0 = fmaf(xv[kh][2 * cc + kw],     wgt, c0);
                        c1 = fmaf(xv[kh][2 * cc + kw + 1], wgt, c1);
                    }
                float v = fmaxf(fmaxf(c0, c1), 0.f);
                int wc = w0 - 2 + 4 * c4 + cc;
                if (wc < 0 || wc >= 1024) v = 0.f;
                h1[ib + cc * 16] = (_Float16)v;
            }
            c4 += 16;
            if (c4 >= 17) { c4 -= 17; ++r; }
        }
    }
    __syncthreads();

    // ---- phase 2: conv2 via fp16 MFMA. wave handles h rows {2w,2w+1} x wn0 {0,32} ----
    const int lane  = tid & 63;
    const int wave  = tid >> 6;
    const int laneN = lane & 31;
    const int icoff = (lane >> 5) * 8;
    const int half  = lane >> 5;

    f32x16 acc[4];
    #pragma unroll
    for (int nt = 0; nt < 4; ++nt)
        #pragma unroll
        for (int r = 0; r < 16; ++r) acc[nt][r] = 0.f;

    const f16x8* Ag = (const f16x8*)fragg;
    f16x8 a_cur = Ag[lane];                          // tap 0 (L1/L2-resident)
    for (int t = 0; t < 15; ++t) {
        f16x8 a_nxt = (t < 14) ? Ag[(t + 1) * 64 + lane] : a_cur;  // 1-deep prefetch
        int kh = t / 5, kw = t - kh * 5;             // wave-uniform
        #pragma unroll
        for (int nt = 0; nt < 4; ++nt) {
            int hrow = 2 * wave + (nt >> 1);
            int wn0  = (nt & 1) * 32;
            int idx  = ((hrow + kh) * 68 + wn0 + laneN + kw) * 16 + icoff;
            f16x8 bv = *(const f16x8*)&h1[idx];
            acc[nt] = __builtin_amdgcn_mfma_f32_32x32x16_f16(a_cur, bv, acc[nt], 0, 0, 0);
        }
        a_cur = a_nxt;
    }

    // ---- epilogue: +bias, relu(maxpool) via xor-1 pair, sum over n, per-oc write ----
    float b2v[16], sums[16];
    #pragma unroll
    for (int r = 0; r < 16; ++r) {
        b2v[r]  = b2[(r & 3) + 8 * (r >> 2) + 4 * half];
        sums[r] = 0.f;
    }
    #pragma unroll
    for (int nt = 0; nt < 4; ++nt)
        #pragma unroll
        for (int r = 0; r < 16; ++r) {
            float d = acc[nt][r] + b2v[r];
            float o = fmaxf(fmaxf(d, __shfl_xor(d, 1)), 0.f);  // pool pair + relu
            sums[r] += o;                                       // counts each pair twice
        }
    #pragma unroll
    for (int r = 0; r < 16; ++r)
        #pragma unroll
        for (int k = 1; k <= 16; k <<= 1)
            sums[r] += __shfl_xor(sums[r], k);                  // sum over n (stays in half)
    if (laneN == 0) {
        #pragma unroll
        for (int r = 0; r < 16; ++r) {
            int oc = (r & 3) + 8 * (r >> 2) + 4 * half;
            part[((b * 32 + oc) * 16 + wt) * 4 + wave] = 0.5f * sums[r];
        }
    }
}

__global__ void tail_kernel(
    const float* __restrict__ part,
    const float* __restrict__ w_glob, const float* __restrict__ b_glob,
    const float* __restrict__ g_glob, const float* __restrict__ be_glob,
    const float* __restrict__ in_proj_w, const float* __restrict__ in_proj_b,
    const float* __restrict__ out_w, const float* __restrict__ out_b,
    const float* __restrict__ mlp_w1, const float* __restrict__ mlp_b1,
    const float* __restrict__ mlp_w2, const float* __restrict__ mlp_b2,
    float* __restrict__ out)
{
    const int b = blockIdx.x;        // 0..63
    const int e = threadIdx.x;       // 0..63 (one wave)
    __shared__ float gs[32], glob_s[64], vs[64], aos[64], hms[32];

    if (e < 32) {
        float sm = 0.f;
        #pragma unroll
        for (int t = 0; t < 64; ++t) sm += part[(b * 32 + e) * 64 + t];
        gs[e] = sm * (1.f / 4096.f);  // mean over 8*512
    }
    __syncthreads();

    float acc = b_glob[e];
    #pragma unroll
    for (int i = 0; i < 32; ++i) acc = fmaf(gs[i], w_glob[i * 64 + e], acc);
    acc = fmaxf(acc, 0.f);

    float m = acc;
    #pragma unroll
    for (int k = 32; k >= 1; k >>= 1) m += __shfl_xor(m, k);
    m *= (1.f / 64.f);
    float d = acc - m;
    float vv = d * d;
    #pragma unroll
    for (int k = 32; k >= 1; k >>= 1) vv += __shfl_xor(vv, k);
    vv *= (1.f / 64.f);
    float gl = d * (1.f / sqrtf(vv + 1e-5f)) * g_glob[e] + be_glob[e];
    glob_s[e] = gl;
    __syncthreads();

    float vval = in_proj_b[128 + e];
    #pragma unroll
    for (int j = 0; j < 64; ++j) vval = fmaf(glob_s[j], in_proj_w[(128 + e) * 64 + j], vval);
    vs[e] = vval;
    __syncthreads();

    float ao = out_b[e];
    #pragma unroll
    for (int j = 0; j < 64; ++j) ao = fmaf(vs[j], out_w[e * 64 + j], ao);
    aos[e] = ao;
    __syncthreads();

    if (e < 32) {
        float hm = mlp_b1[e];
        #pragma unroll
        for (int j = 0; j < 64; ++j) hm = fmaf(aos[j], mlp_w1[j * 32 + e], hm);
        hms[e] = fmaxf(hm, 0.f);
    }
    __syncthreads();

    if (e < 10) {
        float o = mlp_b2[e];
        #pragma unroll
        for (int i = 0; i < 32; ++i) o = fmaf(hms[i], mlp_w2[i * 10 + e], o);
        out[b * 10 + e] = o;
    }
}

extern "C" void kernel_launch(void* const* d_in, const int* in_sizes, int n_in,
                              void* d_out, int out_size, void* d_ws, size_t ws_size,
                              hipStream_t stream) {
    const float* x        = (const float*)d_in[0];
    const float* conv1_w  = (const float*)d_in[6];
    const float* conv1_b  = (const float*)d_in[7];
    const float* conv2_w  = (const float*)d_in[8];
    const float* conv2_b  = (const float*)d_in[9];
    const float* w_glob   = (const float*)d_in[10];
    const float* b_glob   = (const float*)d_in[11];
    const float* g_glob   = (const float*)d_in[12];
    const float* be_glob  = (const float*)d_in[13];
    const float* in_proj_w = (const float*)d_in[14];
    const float* in_proj_b = (const float*)d_in[15];
    const float* out_w    = (const float*)d_in[16];
    const float* out_b    = (const float*)d_in[17];
    const float* mlp_w1   = (const float*)d_in[18];
    const float* mlp_b1   = (const float*)d_in[19];
    const float* mlp_w2   = (const float*)d_in[20];
    const float* mlp_b2   = (const float*)d_in[21];

    _Float16* fragg = (_Float16*)d_ws;                            // 15*64*8*2 = 15360 B
    float* partials = (float*)((char*)d_ws + 15360);              // 64*32*16*4 floats

    prep_frags<<<15, 64, 0, stream>>>(conv2_w, fragg);

    dim3 grid(NT, 64);
    conv_fused<<<grid, 256, 0, stream>>>(x, conv1_w, conv1_b, conv2_b, fragg, partials);

    tail_kernel<<<64, 64, 0, stream>>>(partials, w_glob, b_glob, g_glob, be_glob,
                                       in_proj_w, in_proj_b, out_w, out_b,
                                       mlp_w1, mlp_b1, mlp_w2, mlp_b2,
                                       (float*)d_out);
}

// Round 8
// 123.517 us; speedup vs baseline: 1.8927x; 1.0110x over previous
//
#include <hip/hip_runtime.h>
#include <math.h>

// Live dataflow (softmax over singleton axis == 1.0):
//   x (64,8,2048) -> conv1(16,1,3,5 pad(1,2)) +bias,relu -> maxpool W/2 -> (64,16,8,1024)
//   -> conv2(32,16,3,5 pad(1,2)) +bias,relu -> maxpool W/2 -> mean(H,W) -> g (64,32)
//   -> glob = LN(relu(g@w_glob+b_glob)) -> v = glob@wv.T+bv -> ao = v@out_w.T+out_b
//   -> hmid = relu(ao@mlp_w1+mlp_b1) -> out = hmid@mlp_w2+mlp_b2  (64,10)
//
// conv2: single-product fp16 MFMA 32x32x16 (validated round 6: absmax 1.2e-4 << 7.5e-4).
// Round 8: round-7 plan with DPP ctrl as template constant (builtin requires literal).

typedef __attribute__((ext_vector_type(4))) _Float16 f16x4;
typedef __attribute__((ext_vector_type(8)))  _Float16 f16x8;
typedef __attribute__((ext_vector_type(16))) float    f32x16;

#define WT 64
#define NT 16
#define H1_OFF   0          // 10 rows * 68 cols * 16 ic * 2B = 21760
#define XS_OFF   21760      // 8*144*4 = 4608
#define LDS_BYTES 26368

template <int CTRL>
__device__ __forceinline__ float dppf(float v) {
    return __uint_as_float(__builtin_amdgcn_update_dpp(
        0u, __float_as_uint(v), CTRL, 0xF, 0xF, true));
}
#define DPP_XOR1 0xB1       // quad_perm [1,0,3,2]
#define DPP_XOR2 0x4E       // quad_perm [2,3,0,1]
#define DPP_ROR4 0x124      // row_ror:4
#define DPP_ROR8 0x128      // row_ror:8

// Build conv2-weight fp16 MFMA A-fragments once: fragg[15][64][8]
__global__ void prep_frags(const float* __restrict__ w2, _Float16* __restrict__ fragg) {
    const int t    = blockIdx.x;       // 0..14 (tap)
    const int lane = threadIdx.x;      // 0..63
    const int kh   = t / 5, kw = t - kh * 5;
    const int oc   = lane & 31;
    const int ic0  = (lane >> 5) * 8;
    f16x8 hv;
    #pragma unroll
    for (int j = 0; j < 8; ++j)
        hv[j] = (_Float16)w2[((oc * 16 + ic0 + j) * 3 + kh) * 5 + kw];
    *(f16x8*)&fragg[(t * 64 + lane) * 8] = hv;
}

__global__ __launch_bounds__(256, 4) void conv_fused(
    const float* __restrict__ x,
    const float* __restrict__ w1, const float* __restrict__ b1,
    const float* __restrict__ b2,
    const _Float16* __restrict__ fragg,
    float* __restrict__ part)    // [64 b][32 oc][16 wt][4 wave][2 nhalf]
{
    const int wt  = blockIdx.x;      // 0..15
    const int b   = blockIdx.y;      // 0..63
    const int tid = threadIdx.x;     // 0..255
    const int w0  = wt * WT;

    __shared__ __align__(16) unsigned int ldsu[LDS_BYTES / 4];
    _Float16* h1 = (_Float16*)((char*)ldsu + H1_OFF);  // [(rr*68+c)*16+ic], rr=0..9 (0,9 zero)
    float*    xs = (float*)((char*)ldsu + XS_OFF);     // [8][144]

    // ---- per-thread conv1 weights: ic quad q = tid&3 (thread-constant) ----
    const int q = tid & 3;
    float wreg[60];
    float bias1[4];
    #pragma unroll
    for (int j = 0; j < 4; ++j) {
        #pragma unroll
        for (int k = 0; k < 15; ++k) wreg[j * 15 + k] = w1[(q * 4 + j) * 15 + k];
        bias1[j] = b1[q * 4 + j];
    }

    // ---- phase 0: stage x tile (cols t0..t0+139), zero pad rows rr=0,9 ----
    const int t0 = 2 * w0 - 6;
    for (int i = tid; i < 8 * 144; i += 256) {
        int r = i / 144, tl = i - r * 144;
        int t = t0 + tl;
        float v = 0.f;
        if (tl < 140 && t >= 0 && t < 2048) v = x[(b * 8 + r) * 2048 + t];
        xs[i] = v;
    }
    {
        unsigned int* hh = (unsigned int*)h1;
        for (int i = tid; i < 544; i += 256) {       // each padded row = 544 dwords
            hh[i] = 0u; hh[4896 + i] = 0u;
        }
    }
    __syncthreads();

    // ---- phase 1: conv1 + bias + relu + maxpool -> h1 (fp16) ----
    // item id e in [0,544): idx = e>>2 in [0,136) -> (r = idx/17, c4 = idx%17); quad q = e&3.
    // thread handles items {tid, tid+256} and (tid<32) item tid+512 -> q == tid&3 for all.
    #pragma unroll
    for (int pass = 0; pass < 3; ++pass) {
        if (pass == 2 && tid >= 32) break;
        const int idx = (tid >> 2) + pass * 64;      // 0..135
        const int r   = idx / 17;
        const int c4  = idx - r * 17;
        const int cb  = c4 * 8;
        float xv[3][12];
        #pragma unroll
        for (int pq = 0; pq < 3; ++pq) {
            int rr = r + pq - 1;
            if (rr >= 0 && rr < 8) {
                const float4* p = (const float4*)&xs[rr * 144 + cb];
                float4 a0 = p[0], a1 = p[1], a2 = p[2];
                xv[pq][0]=a0.x; xv[pq][1]=a0.y; xv[pq][2]=a0.z; xv[pq][3]=a0.w;
                xv[pq][4]=a1.x; xv[pq][5]=a1.y; xv[pq][6]=a1.z; xv[pq][7]=a1.w;
                xv[pq][8]=a2.x; xv[pq][9]=a2.y; xv[pq][10]=a2.z; xv[pq][11]=a2.w;
            } else {
                #pragma unroll
                for (int z = 0; z < 12; ++z) xv[pq][z] = 0.f;
            }
        }
        #pragma unroll
        for (int cc = 0; cc < 4; ++cc) {
            const int wc = w0 - 2 + 4 * c4 + cc;
            f16x4 hv;
            #pragma unroll
            for (int j = 0; j < 4; ++j) {
                float c0 = bias1[j], c1 = bias1[j];
                #pragma unroll
                for (int kh = 0; kh < 3; ++kh)
                    #pragma unroll
                    for (int kw = 0; kw < 5; ++kw) {
                        float wgt = wreg[j * 15 + kh * 5 + kw];
                        c0 = fmaf(xv[kh][2 * cc + kw],     wgt, c0);
                        c1 = fmaf(xv[kh][2 * cc + kw + 1], wgt, c1);
                    }
                float v = fmaxf(fmaxf(c0, c1), 0.f);
                if (wc < 0 || wc >= 1024) v = 0.f;
                hv[j] = (_Float16)v;
            }
            *(f16x4*)&h1[((r + 1) * 68 + 4 * c4 + cc) * 16 + q * 4] = hv;  // 8B store
        }
    }
    __syncthreads();

    // ---- phase 2: conv2 via fp16 MFMA. wave handles h rows {2w,2w+1} x wn0 {0,32} ----
    const int lane  = tid & 63;
    const int wave  = tid >> 6;
    const int laneN = lane & 31;
    const int icoff = (lane >> 5) * 8;
    const int half  = lane >> 5;

    f32x16 acc[4];
    #pragma unroll
    for (int nt = 0; nt < 4; ++nt)
        #pragma unroll
        for (int r = 0; r < 16; ++r) acc[nt][r] = 0.f;

    const f16x8* Ag = (const f16x8*)fragg;
    f16x8 a_cur = Ag[lane];                          // tap 0 (L1/L2-resident)
    for (int t = 0; t < 15; ++t) {
        f16x8 a_nxt = (t < 14) ? Ag[(t + 1) * 64 + lane] : a_cur;  // 1-deep prefetch
        int kh = t / 5, kw = t - kh * 5;             // wave-uniform
        #pragma unroll
        for (int nt = 0; nt < 4; ++nt) {
            int hrow = 2 * wave + (nt >> 1);
            int wn0  = (nt & 1) * 32;
            int idx  = ((hrow + kh) * 68 + wn0 + laneN + kw) * 16 + icoff;
            f16x8 bv = *(const f16x8*)&h1[idx];
            acc[nt] = __builtin_amdgcn_mfma_f32_32x32x16_f16(a_cur, bv, acc[nt], 0, 0, 0);
        }
        a_cur = a_nxt;
    }

    // ---- epilogue (VALU/DPP): +bias, relu(maxpool) via DPP xor1, 16-lane DPP sum ----
    float b2v[16], sums[16];
    #pragma unroll
    for (int r = 0; r < 16; ++r) {
        b2v[r]  = b2[(r & 3) + 8 * (r >> 2) + 4 * half];
        sums[r] = 0.f;
    }
    #pragma unroll
    for (int nt = 0; nt < 4; ++nt)
        #pragma unroll
        for (int r = 0; r < 16; ++r) {
            float d = acc[nt][r] + b2v[r];
            float o = fmaxf(fmaxf(d, dppf<DPP_XOR1>(d)), 0.f);  // pool pair + relu
            sums[r] += o;                                        // counts each pair twice
        }
    #pragma unroll
    for (int r = 0; r < 16; ++r) {
        float s = sums[r];
        s += dppf<DPP_XOR1>(s);
        s += dppf<DPP_XOR2>(s);
        s += dppf<DPP_ROR4>(s);
        s += dppf<DPP_ROR8>(s);      // full sum within each 16-lane group
        sums[r] = s;
    }
    if ((lane & 15) == 0) {          // lanes 0,16,32,48: two n-halves x two K-halves
        const int nh = (lane >> 4) & 1;
        #pragma unroll
        for (int r = 0; r < 16; ++r) {
            int oc = (r & 3) + 8 * (r >> 2) + 4 * half;
            part[((b * 32 + oc) * 16 + wt) * 8 + wave * 2 + nh] = 0.5f * sums[r];
        }
    }
}

__global__ void tail_kernel(
    const float* __restrict__ part,
    const float* __restrict__ w_glob, const float* __restrict__ b_glob,
    const float* __restrict__ g_glob, const float* __restrict__ be_glob,
    const float* __restrict__ in_proj_w, const float* __restrict__ in_proj_b,
    const float* __restrict__ out_w, const float* __restrict__ out_b,
    const float* __restrict__ mlp_w1, const float* __restrict__ mlp_b1,
    const float* __restrict__ mlp_w2, const float* __restrict__ mlp_b2,
    float* __restrict__ out)
{
    const int b = blockIdx.x;        // 0..63
    const int e = threadIdx.x;       // 0..63 (one wave)
    __shared__ float gs[32], glob_s[64], vs[64], aos[64], hms[32];

    if (e < 32) {
        float sm = 0.f;
        #pragma unroll
        for (int t = 0; t < 128; ++t) sm += part[(b * 32 + e) * 128 + t];
        gs[e] = sm * (1.f / 4096.f);  // mean over 8*512
    }
    __syncthreads();

    float acc = b_glob[e];
    #pragma unroll
    for (int i = 0; i < 32; ++i) acc = fmaf(gs[i], w_glob[i * 64 + e], acc);
    acc = fmaxf(acc, 0.f);

    float m = acc;
    #pragma unroll
    for (int k = 32; k >= 1; k >>= 1) m += __shfl_xor(m, k);
    m *= (1.f / 64.f);
    float d = acc - m;
    float vv = d * d;
    #pragma unroll
    for (int k = 32; k >= 1; k >>= 1) vv += __shfl_xor(vv, k);
    vv *= (1.f / 64.f);
    float gl = d * (1.f / sqrtf(vv + 1e-5f)) * g_glob[e] + be_glob[e];
    glob_s[e] = gl;
    __syncthreads();

    float vval = in_proj_b[128 + e];
    #pragma unroll
    for (int j = 0; j < 64; ++j) vval = fmaf(glob_s[j], in_proj_w[(128 + e) * 64 + j], vval);
    vs[e] = vval;
    __syncthreads();

    float ao = out_b[e];
    #pragma unroll
    for (int j = 0; j < 64; ++j) ao = fmaf(vs[j], out_w[e * 64 + j], ao);
    aos[e] = ao;
    __syncthreads();

    if (e < 32) {
        float hm = mlp_b1[e];
        #pragma unroll
        for (int j = 0; j < 64; ++j) hm = fmaf(aos[j], mlp_w1[j * 32 + e], hm);
        hms[e] = fmaxf(hm, 0.f);
    }
    __syncthreads();

    if (e < 10) {
        float o = mlp_b2[e];
        #pragma unroll
        for (int i = 0; i < 32; ++i) o = fmaf(hms[i], mlp_w2[i * 10 + e], o);
        out[b * 10 + e] = o;
    }
}

extern "C" void kernel_launch(void* const* d_in, const int* in_sizes, int n_in,
                              void* d_out, int out_size, void* d_ws, size_t ws_size,
                              hipStream_t stream) {
    const float* x        = (const float*)d_in[0];
    const float* conv1_w  = (const float*)d_in[6];
    const float* conv1_b  = (const float*)d_in[7];
    const float* conv2_w  = (const float*)d_in[8];
    const float* conv2_b  = (const float*)d_in[9];
    const float* w_glob   = (const float*)d_in[10];
    const float* b_glob   = (const float*)d_in[11];
    const float* g_glob   = (const float*)d_in[12];
    const float* be_glob  = (const float*)d_in[13];
    const float* in_proj_w = (const float*)d_in[14];
    const float* in_proj_b = (const float*)d_in[15];
    const float* out_w    = (const float*)d_in[16];
    const float* out_b    = (const float*)d_in[17];
    const float* mlp_w1   = (const float*)d_in[18];
    const float* mlp_b1   = (const float*)d_in[19];
    const float* mlp_w2   = (const float*)d_in[20];
    const float* mlp_b2   = (const float*)d_in[21];

    _Float16* fragg = (_Float16*)d_ws;                            // 15*64*8*2 = 15360 B
    float* partials = (float*)((char*)d_ws + 15360);              // 64*32*16*8 floats = 1 MB

    prep_frags<<<15, 64, 0, stream>>>(conv2_w, fragg);

    dim3 grid(NT, 64);
    conv_fused<<<grid, 256, 0, stream>>>(x, conv1_w, conv1_b, conv2_b, fragg, partials);

    tail_kernel<<<64, 64, 0, stream>>>(partials, w_glob, b_glob, g_glob, be_glob,
                                       in_proj_w, in_proj_b, out_w, out_b,
                                       mlp_w1, mlp_b1, mlp_w2, mlp_b2,
                                       (float*)d_out);
}